// Round 4
// baseline (398.756 us; speedup 1.0000x reference)
//
#include <hip/hip_runtime.h>
#include <hip/hip_bf16.h>

// RelAttention (Transformer-XL style) on MI355X.
// fp32 in/out; internal bf16 MFMA w/ fp32 accum.
// B=4, S=1024, D=1024, H=16, DH=64, BH=64. SCALE = 1/32.
//
// Pipeline: cvt -> fused QKV GEMM (m97-style; Q PRE-SCALED by log2e/32)
// -> fused rel-attention (64-row tiles, COLUMN-HALVED flash structure:
// two 512-col passes over a 64 KiB P-LDS -> 2 blocks/CU, 4 waves/SIMD
// to hide LDS/L2 latency; swapped-operand MFMA, packed u16x4 LDS)
// -> final GEMM (64x64 tiles, 4 blocks/CU).

typedef __bf16 bf16x8 __attribute__((ext_vector_type(8)));
typedef float  f32x4  __attribute__((ext_vector_type(4)));
typedef unsigned short u16x4 __attribute__((ext_vector_type(4)));

struct alignas(16) U128 { unsigned long long lo, hi; };

__device__ __forceinline__ bf16x8 ldg8(const __hip_bfloat16* p) {
    U128 u = *reinterpret_cast<const U128*>(p);
    return __builtin_bit_cast(bf16x8, u);
}

__device__ __forceinline__ __bf16 f2b(float f) {
    __hip_bfloat16 h = __float2bfloat16(f);
    return __builtin_bit_cast(__bf16, h);
}
__device__ __forceinline__ unsigned short f2bu(float f) {
    __hip_bfloat16 h = __float2bfloat16(f);
    return __builtin_bit_cast(unsigned short, h);
}
__device__ __forceinline__ float b2f(__bf16 b) {
    __hip_bfloat16 h = __builtin_bit_cast(__hip_bfloat16, b);
    return __bfloat162float(h);
}
__device__ __forceinline__ float bu2f(unsigned short u) {
    __hip_bfloat16 h = __builtin_bit_cast(__hip_bfloat16, u);
    return __bfloat162float(h);
}

__device__ __forceinline__ bf16x8 ldg8cvt(const float* p) {
    f32x4 a = *reinterpret_cast<const f32x4*>(p);
    f32x4 b = *reinterpret_cast<const f32x4*>(p + 4);
    bf16x8 r;
    r[0] = f2b(a[0]); r[1] = f2b(a[1]); r[2] = f2b(a[2]); r[3] = f2b(a[3]);
    r[4] = f2b(b[0]); r[5] = f2b(b[1]); r[6] = f2b(b[2]); r[7] = f2b(b[3]);
    return r;
}

#define MFMA16(a, b, c) __builtin_amdgcn_mfma_f32_16x16x32_bf16((a), (b), (c), 0, 0, 0)

// C1 = log2(e) * SCALE = log2(e)/32. Q is pre-scaled by this so the
// softmax exponent is exp2(bd' + ac') with NO fma and NO shift constant.
#define C1F 0.0450843334f

__device__ __forceinline__ void gll16(const __hip_bfloat16* g, void* lds_wave_base) {
    __builtin_amdgcn_global_load_lds(
        (const __attribute__((address_space(1))) void*)g,
        (__attribute__((address_space(3))) void*)lds_wave_base,
        16, 0, 0);
}

// ---------------------------------------------------------------------------
// fp32 -> bf16: x(4M), pos(4M), Wq/Wk/Wv(3M stacked), Wc(1M) = 12M elems.
// ---------------------------------------------------------------------------
__global__ __launch_bounds__(256) void cvt_kernel(
    const float* __restrict__ x,  const float* __restrict__ pos,
    const float* __restrict__ wq, const float* __restrict__ wk,
    const float* __restrict__ wv, const float* __restrict__ wc,
    __hip_bfloat16* __restrict__ xb, __hip_bfloat16* __restrict__ posb,
    __hip_bfloat16* __restrict__ wqkvb, __hip_bfloat16* __restrict__ wcb)
{
    const size_t base = ((size_t)blockIdx.x * 256 + threadIdx.x) * 8;
    const size_t M1 = (size_t)1 << 20;
    const float* src; __hip_bfloat16* dst; size_t o;
    if (base < 4*M1)        { src = x;   dst = xb;           o = base; }
    else if (base < 8*M1)   { src = pos; dst = posb;         o = base - 4*M1; }
    else if (base < 9*M1)   { src = wq;  dst = wqkvb;        o = base - 8*M1; }
    else if (base < 10*M1)  { src = wk;  dst = wqkvb + M1;   o = base - 9*M1; }
    else if (base < 11*M1)  { src = wv;  dst = wqkvb + 2*M1; o = base - 10*M1; }
    else                    { src = wc;  dst = wcb;          o = base - 11*M1; }
    *(bf16x8*)(dst + o) = ldg8cvt(src + o);
}

// ---------------------------------------------------------------------------
// QKV GEMM (m97-style): C[m][n] = sum_k A[m][k]*Bm[n][k], Bm=[3072][1024].
// n<1024 -> Qu = (C+bq+u)*C1 (PRE-SCALED); <2048 -> Kb = C+bk;
// else Vt head-transposed = C+bv.
// ---------------------------------------------------------------------------
__global__ __launch_bounds__(256) void gemm_qkv(
    const __hip_bfloat16* __restrict__ A,
    const __hip_bfloat16* __restrict__ Bm,
    const float* __restrict__ bq, const float* __restrict__ bk,
    const float* __restrict__ bv, const float* __restrict__ u,
    __hip_bfloat16* __restrict__ Qu,
    __hip_bfloat16* __restrict__ Kb, __hip_bfloat16* __restrict__ Vt)
{
    __shared__ __hip_bfloat16 As[128 * 32];
    __shared__ __hip_bfloat16 Bs[128 * 32];

    const int tid  = threadIdx.x;
    const int lane = tid & 63, w = tid >> 6;
    const int quad = lane >> 4, c16 = lane & 15;
    const int wm = w >> 1, wn = w & 1;
    const int m0 = blockIdx.y * 128;
    const int n0 = blockIdx.x * 128;

    const int srow = w * 16 + (lane >> 2);
    const int scol = (lane & 3) * 8;
    const __hip_bfloat16* gA0 = A  + (size_t)(m0 + srow) * 1024 + scol;
    const __hip_bfloat16* gA1 = gA0 + (size_t)64 * 1024;
    const __hip_bfloat16* gB0 = Bm + (size_t)(n0 + srow) * 1024 + scol;
    const __hip_bfloat16* gB1 = gB0 + (size_t)64 * 1024;
    char* ldsA0 = (char*)As + (w << 10);
    char* ldsA1 = ldsA0 + 4096;
    char* ldsB0 = (char*)Bs + (w << 10);
    char* ldsB1 = ldsB0 + 4096;

    f32x4 acc[4][4] = {};

    for (int k0 = 0; k0 < 1024; k0 += 32) {
        gll16(gA0 + k0, ldsA0);
        gll16(gA1 + k0, ldsA1);
        gll16(gB0 + k0, ldsB0);
        gll16(gB1 + k0, ldsB1);
        __syncthreads();

        bf16x8 af[4], bfr[4];
        #pragma unroll
        for (int i = 0; i < 4; ++i) {
            af[i]  = *(const bf16x8*)&As[(wm * 64 + i * 16 + c16) * 32 + quad * 8];
            bfr[i] = *(const bf16x8*)&Bs[(wn * 64 + i * 16 + c16) * 32 + quad * 8];
        }
        #pragma unroll
        for (int mi = 0; mi < 4; ++mi)
            #pragma unroll
            for (int ni = 0; ni < 4; ++ni)
                acc[mi][ni] = MFMA16(af[mi], bfr[ni], acc[mi][ni]);
        __syncthreads();
    }

    #pragma unroll
    for (int mi = 0; mi < 4; ++mi) {
        #pragma unroll
        for (int ni = 0; ni < 4; ++ni) {
            const int m = m0 + wm * 64 + mi * 16 + quad * 4;  // +r
            const int n = n0 + wn * 64 + ni * 16 + c16;
            if (n < 1024) {
                const float b0 = bq[n] + u[n & 63];
                #pragma unroll
                for (int r = 0; r < 4; ++r)
                    Qu[(size_t)(m + r) * 1024 + n] =
                        __float2bfloat16((acc[mi][ni][r] + b0) * C1F);
            } else if (n < 2048) {
                const int nn = n - 1024;
                const float b0 = bk[nn];
                #pragma unroll
                for (int r = 0; r < 4; ++r)
                    Kb[(size_t)(m + r) * 1024 + nn] =
                        __float2bfloat16(acc[mi][ni][r] + b0);
            } else {
                const int nn = n - 2048;
                const float b0 = bv[nn];
                const int d = nn & 63, hh = nn >> 6;
                const int bb = m >> 10, s = m & 1023;
                u16x4 pk;
                #pragma unroll
                for (int r = 0; r < 4; ++r)
                    pk[r] = f2bu(acc[mi][ni][r] + b0);
                *(u16x4*)&Vt[(((size_t)(bb * 16 + hh) * 64 + d) << 10) + s] = pk;
            }
        }
    }
}

// ---------------------------------------------------------------------------
// Final GEMM, 64x64 tiles (grid 16x64 = 1024 blocks -> 4 blocks/CU).
// ---------------------------------------------------------------------------
__global__ __launch_bounds__(256) void gemm_fin64(
    const __hip_bfloat16* __restrict__ A,
    const __hip_bfloat16* __restrict__ Bm,
    float* __restrict__ dout, const float* __restrict__ bc)
{
    __shared__ __hip_bfloat16 As[64 * 32];
    __shared__ __hip_bfloat16 Bs[64 * 32];

    const int tid  = threadIdx.x;
    const int lane = tid & 63, w = tid >> 6;
    const int quad = lane >> 4, c16 = lane & 15;
    const int wm = w >> 1, wn = w & 1;
    const int m0 = blockIdx.y * 64;
    const int n0 = blockIdx.x * 64;

    const int srow = w * 16 + (lane >> 2);
    const int scol = (lane & 3) * 8;
    const __hip_bfloat16* gA = A  + (size_t)(m0 + srow) * 1024 + scol;
    const __hip_bfloat16* gB = Bm + (size_t)(n0 + srow) * 1024 + scol;
    char* ldsA = (char*)As + (w << 10);
    char* ldsB = (char*)Bs + (w << 10);

    f32x4 acc[2][2] = {};

    for (int k0 = 0; k0 < 1024; k0 += 32) {
        gll16(gA + k0, ldsA);
        gll16(gB + k0, ldsB);
        __syncthreads();

        bf16x8 af[2], bfr[2];
        #pragma unroll
        for (int i = 0; i < 2; ++i) {
            af[i]  = *(const bf16x8*)&As[(wm * 32 + i * 16 + c16) * 32 + quad * 8];
            bfr[i] = *(const bf16x8*)&Bs[(wn * 32 + i * 16 + c16) * 32 + quad * 8];
        }
        #pragma unroll
        for (int mi = 0; mi < 2; ++mi)
            #pragma unroll
            for (int ni = 0; ni < 2; ++ni)
                acc[mi][ni] = MFMA16(af[mi], bfr[ni], acc[mi][ni]);
        __syncthreads();
    }

    #pragma unroll
    for (int mi = 0; mi < 2; ++mi) {
        #pragma unroll
        for (int ni = 0; ni < 2; ++ni) {
            const int m = m0 + wm * 32 + mi * 16 + quad * 4;
            const int n = n0 + wn * 32 + ni * 16 + c16;
            const float b0 = bc[n];
            #pragma unroll
            for (int r = 0; r < 4; ++r)
                dout[(size_t)(m + r) * 1024 + n] = acc[mi][ni][r] + b0;
        }
    }
}

// ---------------------------------------------------------------------------
// Fused relative attention, 64-row tiles, 512 threads (8 waves),
// COLUMN-HALVED: two passes over 512-col halves; P-LDS 64x512 = 64 KiB ->
// 2 blocks/CU (4 waves/SIMD) for latency hiding at ~equal total work.
// Grid (bh, i0-tile): block ids of one head congruent mod 8 -> same XCD.
//
// Rel-shift: raw[j][l] -> col cc=(l+j+1)&1023, row j (wrapped) else j-1.
// Per half, the needed raw-l values form a 576-wide window mod 1024 ->
// 37 l-tiles statically split across 8 waves (5/5/5/5/5/4/4/4); stores
// masked to the half. PV accumulates in registers across passes; row
// sums accumulate too. Qu pre-scaled by log2e/32; exp2(bd'+ac') direct.
// ---------------------------------------------------------------------------
__device__ __forceinline__ int lidx9(int row, int c) {
    return (row << 9) + ((((c >> 3) ^ row) << 3) | (c & 7));
}

__global__ __launch_bounds__(512, 4) void attn_kernel(
    const __hip_bfloat16* __restrict__ Qu,   // [4096][1024] (q+bq+u)*C1
    const __hip_bfloat16* __restrict__ Kb,   // [4096][1024]
    const __hip_bfloat16* __restrict__ Posb, // [4096][1024] bf16 pos
    const __hip_bfloat16* __restrict__ Vt,   // [bh*64+d][s]
    const float* __restrict__ uvec, const float* __restrict__ vvec,
    __hip_bfloat16* __restrict__ O)          // [4096][1024]
{
    __shared__ __attribute__((aligned(16))) __hip_bfloat16 Ls[64 * 512]; // 64 KiB
    __shared__ float Wsum[64 * 8];             // per-(row, wave) partial sums
    __shared__ float rs[64];                   // per-row 1/sum

    const int tid  = threadIdx.x;
    const int lane = tid & 63, w = tid >> 6;   // w in [0,8)
    const int quad = lane >> 4, c16 = lane & 15;
    const int i0 = blockIdx.y * 64;            // row tile
    const int bh = blockIdx.x;                 // head (XCD-local: id % 8 = bh % 8)
    const int b = bh >> 4, h = bh & 15;
    const size_t headoff = (size_t)h * 64;
    const size_t tokbase = (size_t)b * 1024;
    const int j2 = i0 + 64;
    const bool havej2 = (j2 < 1024);

    // Per-group Qu fragment pointers (group g = rows i0+g*16 .. +15).
    const __hip_bfloat16* qup0 =
        Qu + (tokbase + i0 + c16) * 1024 + headoff + quad * 8;

    // Phase-2 l-tile split: 37 tiles over 8 waves.
    const int ntile = (w < 5) ? 5 : 4;
    const int tbase = (w < 5) ? w * 5 : 25 + (w - 5) * 4;

    // PV accumulator and row-sum accumulate ACROSS the two passes.
    f32x4 obacc[4] = {};
    float rsum[4] = {0.f, 0.f, 0.f, 0.f};
    const int d0 = (w & 3) * 16;
    const int kh = w >> 2;
    const __hip_bfloat16* vp =
        Vt + ((size_t)bh * 64 + d0 + c16) * 1024 + quad * 8;

    for (int ph = 0; ph < 2; ++ph) {
        const int h0 = ph << 9;

        // Zero col for rows whose (i+1) falls in this half.
        if (tid < 64) {
            const int c = i0 + tid + 1;
            if (c < 1024 && ((c ^ h0) & 512) == 0)
                Ls[lidx9(tid, c & 511)] = __float2bfloat16(0.f);
        }

        // Load au frags; derive av = au + (v-u)*C1 in-register (per pass
        // to keep liveness short; loads are L2/L1-hot).
        float dvuA[8], dvuB[8];
        #pragma unroll
        for (int j = 0; j < 8; ++j) {
            const int d = quad * 8 + j;
            dvuA[j] = (vvec[d]      - uvec[d])      * C1F;
            dvuB[j] = (vvec[d + 32] - uvec[d + 32]) * C1F;
        }
        bf16x8 au[4][2], av[4][2];
        #pragma unroll
        for (int g = 0; g < 4; ++g) {
            au[g][0] = ldg8(qup0 + (size_t)g * 16 * 1024);
            au[g][1] = ldg8(qup0 + (size_t)g * 16 * 1024 + 32);
            #pragma unroll
            for (int j = 0; j < 8; ++j) {
                av[g][0][j] = f2b(b2f(au[g][0][j]) + dvuA[j]);
                av[g][1][j] = f2b(b2f(au[g][1][j]) + dvuB[j]);
            }
        }
        bf16x8 a4[2];
        if (havej2) {
            a4[0] = ldg8(qup0 + (size_t)64 * 1024);
            a4[1] = ldg8(qup0 + (size_t)64 * 1024 + 32);
            #pragma unroll
            for (int j = 0; j < 8; ++j) {
                a4[0][j] = f2b(b2f(a4[0][j]) + dvuA[j]);
                a4[1][j] = f2b(b2f(a4[1][j]) + dvuB[j]);
            }
        }

        // Phase 2: windowed BD scatter for this half.
        // Window start: l = (h0 - i0 - 65) mod 1024, aligned down to tile.
        const int Tstart = ((h0 - i0 - 65) & 1023) >> 4;
        for (int s = 0; s < ntile; ++s) {
            const int tl = (Tstart + tbase + s) & 63;
            const int l0 = tl << 4;
            const __hip_bfloat16* rp =
                Posb + (tokbase + l0 + c16) * 1024 + headoff + quad * 8;
            const bf16x8 r0 = ldg8(rp);
            const bf16x8 r1 = ldg8(rp + 32);
            const int lq = l0 + quad * 4;
            #pragma unroll
            for (int g = 0; g < 4; ++g) {
                f32x4 c = (f32x4){0.f, 0.f, 0.f, 0.f};
                c = MFMA16(r0, av[g][0], c);
                c = MFMA16(r1, av[g][1], c);
                const int jl = g * 16 + c16;
                const int base2 = lq + i0 + jl + 1;   // l + j + 1 at r=0
                const int rwm1 = jl - 1;
                #pragma unroll
                for (int r = 0; r < 4; ++r) {
                    const int t1 = base2 + r;         // <= 2047
                    const int cc = t1 & 1023;
                    const int rw = rwm1 + (t1 >> 10); // +1 iff wrapped
                    if (rw >= 0 && ((cc ^ h0) & 512) == 0)
                        Ls[lidx9(rw, cc & 511)] = __float2bfloat16(c[r]);
                }
            }
            if (havej2) {
                f32x4 c = (f32x4){0.f, 0.f, 0.f, 0.f};
                c = MFMA16(r0, a4[0], c);
                c = MFMA16(r1, a4[1], c);
                if (c16 == 0) {
                    #pragma unroll
                    for (int r = 0; r < 4; ++r) {
                        const int t1 = lq + r + j2 + 1;  // non-wrapped only
                        if (t1 < 1024 && ((t1 ^ h0) & 512) == 0)
                            Ls[lidx9(63, t1 & 511)] = __float2bfloat16(c[r]);
                    }
                }
            }
        }
        __syncthreads();

        // Phase 4: AC' + exp2 for this half's 512 cols (wave strip = 64).
        for (int t = 0; t < 4; ++t) {
            const int c0 = h0 + w * 64 + t * 16;
            const __hip_bfloat16* kp =
                Kb + (tokbase + c0 + c16) * 1024 + headoff + quad * 8;
            const bf16x8 k0 = ldg8(kp);
            const bf16x8 k1 = ldg8(kp + 32);
            const int lc0 = w * 64 + t * 16 + quad * 4;   // local col
            #pragma unroll
            for (int g = 0; g < 4; ++g) {
                f32x4 c = (f32x4){0.f, 0.f, 0.f, 0.f};
                c = MFMA16(k0, au[g][0], c);
                c = MFMA16(k1, au[g][1], c);
                const int jl = g * 16 + c16;
                const int idx = lidx9(jl, lc0);
                const u16x4 bd = *(const u16x4*)&Ls[idx];
                u16x4 pk;
                float s4 = 0.f;
                #pragma unroll
                for (int r = 0; r < 4; ++r) {
                    const float p =
                        __builtin_amdgcn_exp2f(bu2f(bd[r]) + c[r]);
                    s4 += p;
                    pk[r] = f2bu(p);
                }
                *(u16x4*)&Ls[idx] = pk;
                rsum[g] += s4;
            }
        }
        if (ph == 1) {
            // row jl lives in lanes {c16, c16+16, c16+32, c16+48}
            #pragma unroll
            for (int g = 0; g < 4; ++g) {
                float s = rsum[g];
                s += __shfl_xor(s, 16);
                s += __shfl_xor(s, 32);
                if (lane < 16) Wsum[(g * 16 + lane) * 8 + w] = s;
            }
        }
        __syncthreads();

        // rs = 1/rowsum, once Wsum complete (wave-0 lanes; ordered by the
        // phase-4 barrier above and consumed after the post-PV barrier).
        if (ph == 1 && tid < 64) {
            float s = 0.f;
            #pragma unroll
            for (int k = 0; k < 8; ++k) s += Wsum[tid * 8 + k];
            rs[tid] = 1.f / s;
        }

        // Phase 6 partial: PV over this half's 512 cols (kh-half of them
        // per wave), accumulating into obacc across passes.
        for (int kk = kh * 256; kk < kh * 256 + 256; kk += 32) {
            const bf16x8 vld = ldg8(vp + h0 + kk);
            #pragma unroll
            for (int g = 0; g < 4; ++g) {
                const bf16x8 p =
                    *(const bf16x8*)&Ls[lidx9(g * 16 + c16, kk + quad * 8)];
                obacc[g] = MFMA16(p, vld, obacc[g]);
            }
        }
        __syncthreads();   // PV reads done; Ls reusable next pass / epilogue
    }

    // Epilogue: kh=1 waves dump partial O to LDS; kh=0 combines, scales,
    // writes.
    float* Lf = (float*)Ls;
    const int sbase = (w & 3) * 1024;
    if (kh == 1) {
        #pragma unroll
        for (int g = 0; g < 4; ++g)
            #pragma unroll
            for (int r = 0; r < 4; ++r)
                Lf[sbase + g * 256 + (quad * 4 + r) * 16 + c16] = obacc[g][r];
    }
    __syncthreads();
    if (kh == 0) {
        #pragma unroll
        for (int g = 0; g < 4; ++g)
            #pragma unroll
            for (int r = 0; r < 4; ++r) {
                const int il = g * 16 + quad * 4 + r;
                const float val =
                    (obacc[g][r] + Lf[sbase + g * 256 + (quad * 4 + r) * 16 + c16])
                    * rs[il];
                const int i = i0 + il;
                const int d = d0 + c16;
                O[(tokbase + i) * 1024 + headoff + d] = __float2bfloat16(val);
            }
    }
}

// ---------------------------------------------------------------------------
extern "C" void kernel_launch(void* const* d_in, const int* in_sizes, int n_in,
                              void* d_out, int out_size, void* d_ws, size_t ws_size,
                              hipStream_t stream)
{
    const float* x   = (const float*)d_in[0];
    const float* u   = (const float*)d_in[1];
    const float* v   = (const float*)d_in[2];
    const float* pos = (const float*)d_in[3];
    const float* Wq  = (const float*)d_in[4];
    const float* bq  = (const float*)d_in[5];
    const float* Wk  = (const float*)d_in[6];
    const float* bk  = (const float*)d_in[7];
    const float* Wv  = (const float*)d_in[8];
    const float* bv  = (const float*)d_in[9];
    const float* Wc  = (const float*)d_in[10];
    const float* bc  = (const float*)d_in[11];

    const size_t MB = (size_t)1 << 20;
    char* ws = (char*)d_ws;
    __hip_bfloat16* Qu    = (__hip_bfloat16*)(ws + 0 * MB);
    __hip_bfloat16* Kb    = (__hip_bfloat16*)(ws + 8 * MB);
    __hip_bfloat16* Vt    = (__hip_bfloat16*)(ws + 16 * MB);
    __hip_bfloat16* xb    = (__hip_bfloat16*)(ws + 24 * MB);  // aliased w/ O
    __hip_bfloat16* O     = (__hip_bfloat16*)(ws + 24 * MB);  // x dead after QKV
    __hip_bfloat16* Posb  = (__hip_bfloat16*)(ws + 32 * MB);
    __hip_bfloat16* Wqkvb = (__hip_bfloat16*)(ws + 40 * MB);
    __hip_bfloat16* Wcb   = (__hip_bfloat16*)(ws + 46 * MB);

    cvt_kernel<<<6144, 256, 0, stream>>>(x, pos, Wq, Wk, Wv, Wc,
                                         xb, Posb, Wqkvb, Wcb);

    gemm_qkv<<<dim3(24, 32), dim3(256), 0, stream>>>(
        xb, Wqkvb, bq, bk, bv, u, Qu, Kb, Vt);

    attn_kernel<<<dim3(64, 16), dim3(512), 0, stream>>>(
        Qu, Kb, Posb, Vt, u, v, O);

    gemm_fin64<<<dim3(16, 64), dim3(256), 0, stream>>>(
        O, Wcb, (float*)d_out, bc);
}

// Round 5
// 281.239 us; speedup vs baseline: 1.4179x; 1.4179x over previous
//
#include <hip/hip_runtime.h>
#include <hip/hip_bf16.h>

// RelAttention (Transformer-XL style) on MI355X.
// fp32 in/out; internal bf16 MFMA w/ fp32 accum.
// B=4, S=1024, D=1024, H=16, DH=64, BH=64. SCALE = 1/32.
//
// Pipeline: cvt -> fused QKV GEMM (m97-style; Q PRE-SCALED by log2e/32)
// -> fused rel-attention (64-row tiles, COLUMN-HALVED flash structure:
// two 512-col passes over a 64 KiB P-LDS -> 2 blocks/CU, 4 waves/SIMD)
// -> final GEMM (64x64 tiles, 4 blocks/CU).
//
// NOTE on __launch_bounds__: the compiler's VGPR cap is 256-based
// (2nd arg w -> cap 256/w), NOT 512-based. (512,4) capped VGPR at 64 and
// spilled ~900 MB of scratch (r4: FETCH 446 MB, WRITE 448 MB). (512,2)
// caps at 128, which fits this kernel's ~110 and still allows the HW's
// 16 waves/CU (2048-reg pool) with LDS-limited 2 blocks/CU.

typedef __bf16 bf16x8 __attribute__((ext_vector_type(8)));
typedef float  f32x4  __attribute__((ext_vector_type(4)));
typedef unsigned short u16x4 __attribute__((ext_vector_type(4)));

struct alignas(16) U128 { unsigned long long lo, hi; };

__device__ __forceinline__ bf16x8 ldg8(const __hip_bfloat16* p) {
    U128 u = *reinterpret_cast<const U128*>(p);
    return __builtin_bit_cast(bf16x8, u);
}

__device__ __forceinline__ __bf16 f2b(float f) {
    __hip_bfloat16 h = __float2bfloat16(f);
    return __builtin_bit_cast(__bf16, h);
}
__device__ __forceinline__ unsigned short f2bu(float f) {
    __hip_bfloat16 h = __float2bfloat16(f);
    return __builtin_bit_cast(unsigned short, h);
}
__device__ __forceinline__ float b2f(__bf16 b) {
    __hip_bfloat16 h = __builtin_bit_cast(__hip_bfloat16, b);
    return __bfloat162float(h);
}
__device__ __forceinline__ float bu2f(unsigned short u) {
    __hip_bfloat16 h = __builtin_bit_cast(__hip_bfloat16, u);
    return __bfloat162float(h);
}

__device__ __forceinline__ bf16x8 ldg8cvt(const float* p) {
    f32x4 a = *reinterpret_cast<const f32x4*>(p);
    f32x4 b = *reinterpret_cast<const f32x4*>(p + 4);
    bf16x8 r;
    r[0] = f2b(a[0]); r[1] = f2b(a[1]); r[2] = f2b(a[2]); r[3] = f2b(a[3]);
    r[4] = f2b(b[0]); r[5] = f2b(b[1]); r[6] = f2b(b[2]); r[7] = f2b(b[3]);
    return r;
}

#define MFMA16(a, b, c) __builtin_amdgcn_mfma_f32_16x16x32_bf16((a), (b), (c), 0, 0, 0)

// C1 = log2(e) * SCALE = log2(e)/32. Q is pre-scaled by this so the
// softmax exponent is exp2(bd' + ac') with NO fma and NO shift constant.
#define C1F 0.0450843334f

__device__ __forceinline__ void gll16(const __hip_bfloat16* g, void* lds_wave_base) {
    __builtin_amdgcn_global_load_lds(
        (const __attribute__((address_space(1))) void*)g,
        (__attribute__((address_space(3))) void*)lds_wave_base,
        16, 0, 0);
}

// ---------------------------------------------------------------------------
// fp32 -> bf16: x(4M), pos(4M), Wq/Wk/Wv(3M stacked), Wc(1M) = 12M elems.
// ---------------------------------------------------------------------------
__global__ __launch_bounds__(256) void cvt_kernel(
    const float* __restrict__ x,  const float* __restrict__ pos,
    const float* __restrict__ wq, const float* __restrict__ wk,
    const float* __restrict__ wv, const float* __restrict__ wc,
    __hip_bfloat16* __restrict__ xb, __hip_bfloat16* __restrict__ posb,
    __hip_bfloat16* __restrict__ wqkvb, __hip_bfloat16* __restrict__ wcb)
{
    const size_t base = ((size_t)blockIdx.x * 256 + threadIdx.x) * 8;
    const size_t M1 = (size_t)1 << 20;
    const float* src; __hip_bfloat16* dst; size_t o;
    if (base < 4*M1)        { src = x;   dst = xb;           o = base; }
    else if (base < 8*M1)   { src = pos; dst = posb;         o = base - 4*M1; }
    else if (base < 9*M1)   { src = wq;  dst = wqkvb;        o = base - 8*M1; }
    else if (base < 10*M1)  { src = wk;  dst = wqkvb + M1;   o = base - 9*M1; }
    else if (base < 11*M1)  { src = wv;  dst = wqkvb + 2*M1; o = base - 10*M1; }
    else                    { src = wc;  dst = wcb;          o = base - 11*M1; }
    *(bf16x8*)(dst + o) = ldg8cvt(src + o);
}

// ---------------------------------------------------------------------------
// QKV GEMM (m97-style): C[m][n] = sum_k A[m][k]*Bm[n][k], Bm=[3072][1024].
// n<1024 -> Qu = (C+bq+u)*C1 (PRE-SCALED); <2048 -> Kb = C+bk;
// else Vt head-transposed = C+bv.
// ---------------------------------------------------------------------------
__global__ __launch_bounds__(256) void gemm_qkv(
    const __hip_bfloat16* __restrict__ A,
    const __hip_bfloat16* __restrict__ Bm,
    const float* __restrict__ bq, const float* __restrict__ bk,
    const float* __restrict__ bv, const float* __restrict__ u,
    __hip_bfloat16* __restrict__ Qu,
    __hip_bfloat16* __restrict__ Kb, __hip_bfloat16* __restrict__ Vt)
{
    __shared__ __hip_bfloat16 As[128 * 32];
    __shared__ __hip_bfloat16 Bs[128 * 32];

    const int tid  = threadIdx.x;
    const int lane = tid & 63, w = tid >> 6;
    const int quad = lane >> 4, c16 = lane & 15;
    const int wm = w >> 1, wn = w & 1;
    const int m0 = blockIdx.y * 128;
    const int n0 = blockIdx.x * 128;

    const int srow = w * 16 + (lane >> 2);
    const int scol = (lane & 3) * 8;
    const __hip_bfloat16* gA0 = A  + (size_t)(m0 + srow) * 1024 + scol;
    const __hip_bfloat16* gA1 = gA0 + (size_t)64 * 1024;
    const __hip_bfloat16* gB0 = Bm + (size_t)(n0 + srow) * 1024 + scol;
    const __hip_bfloat16* gB1 = gB0 + (size_t)64 * 1024;
    char* ldsA0 = (char*)As + (w << 10);
    char* ldsA1 = ldsA0 + 4096;
    char* ldsB0 = (char*)Bs + (w << 10);
    char* ldsB1 = ldsB0 + 4096;

    f32x4 acc[4][4] = {};

    for (int k0 = 0; k0 < 1024; k0 += 32) {
        gll16(gA0 + k0, ldsA0);
        gll16(gA1 + k0, ldsA1);
        gll16(gB0 + k0, ldsB0);
        gll16(gB1 + k0, ldsB1);
        __syncthreads();

        bf16x8 af[4], bfr[4];
        #pragma unroll
        for (int i = 0; i < 4; ++i) {
            af[i]  = *(const bf16x8*)&As[(wm * 64 + i * 16 + c16) * 32 + quad * 8];
            bfr[i] = *(const bf16x8*)&Bs[(wn * 64 + i * 16 + c16) * 32 + quad * 8];
        }
        #pragma unroll
        for (int mi = 0; mi < 4; ++mi)
            #pragma unroll
            for (int ni = 0; ni < 4; ++ni)
                acc[mi][ni] = MFMA16(af[mi], bfr[ni], acc[mi][ni]);
        __syncthreads();
    }

    #pragma unroll
    for (int mi = 0; mi < 4; ++mi) {
        #pragma unroll
        for (int ni = 0; ni < 4; ++ni) {
            const int m = m0 + wm * 64 + mi * 16 + quad * 4;  // +r
            const int n = n0 + wn * 64 + ni * 16 + c16;
            if (n < 1024) {
                const float b0 = bq[n] + u[n & 63];
                #pragma unroll
                for (int r = 0; r < 4; ++r)
                    Qu[(size_t)(m + r) * 1024 + n] =
                        __float2bfloat16((acc[mi][ni][r] + b0) * C1F);
            } else if (n < 2048) {
                const int nn = n - 1024;
                const float b0 = bk[nn];
                #pragma unroll
                for (int r = 0; r < 4; ++r)
                    Kb[(size_t)(m + r) * 1024 + nn] =
                        __float2bfloat16(acc[mi][ni][r] + b0);
            } else {
                const int nn = n - 2048;
                const float b0 = bv[nn];
                const int d = nn & 63, hh = nn >> 6;
                const int bb = m >> 10, s = m & 1023;
                u16x4 pk;
                #pragma unroll
                for (int r = 0; r < 4; ++r)
                    pk[r] = f2bu(acc[mi][ni][r] + b0);
                *(u16x4*)&Vt[(((size_t)(bb * 16 + hh) * 64 + d) << 10) + s] = pk;
            }
        }
    }
}

// ---------------------------------------------------------------------------
// Final GEMM, 64x64 tiles (grid 16x64 = 1024 blocks -> 4 blocks/CU).
// ---------------------------------------------------------------------------
__global__ __launch_bounds__(256) void gemm_fin64(
    const __hip_bfloat16* __restrict__ A,
    const __hip_bfloat16* __restrict__ Bm,
    float* __restrict__ dout, const float* __restrict__ bc)
{
    __shared__ __hip_bfloat16 As[64 * 32];
    __shared__ __hip_bfloat16 Bs[64 * 32];

    const int tid  = threadIdx.x;
    const int lane = tid & 63, w = tid >> 6;
    const int quad = lane >> 4, c16 = lane & 15;
    const int wm = w >> 1, wn = w & 1;
    const int m0 = blockIdx.y * 64;
    const int n0 = blockIdx.x * 64;

    const int srow = w * 16 + (lane >> 2);
    const int scol = (lane & 3) * 8;
    const __hip_bfloat16* gA = A  + (size_t)(m0 + srow) * 1024 + scol;
    const __hip_bfloat16* gB = Bm + (size_t)(n0 + srow) * 1024 + scol;
    char* ldsA = (char*)As + (w << 10);
    char* ldsB = (char*)Bs + (w << 10);

    f32x4 acc[2][2] = {};

    for (int k0 = 0; k0 < 1024; k0 += 32) {
        gll16(gA + k0, ldsA);
        gll16(gB + k0, ldsB);
        __syncthreads();

        bf16x8 af[2], bfr[2];
        #pragma unroll
        for (int i = 0; i < 2; ++i) {
            af[i]  = *(const bf16x8*)&As[(wm * 32 + i * 16 + c16) * 32 + quad * 8];
            bfr[i] = *(const bf16x8*)&Bs[(wn * 32 + i * 16 + c16) * 32 + quad * 8];
        }
        #pragma unroll
        for (int mi = 0; mi < 2; ++mi)
            #pragma unroll
            for (int ni = 0; ni < 2; ++ni)
                acc[mi][ni] = MFMA16(af[mi], bfr[ni], acc[mi][ni]);
        __syncthreads();
    }

    #pragma unroll
    for (int mi = 0; mi < 2; ++mi) {
        #pragma unroll
        for (int ni = 0; ni < 2; ++ni) {
            const int m = m0 + wm * 32 + mi * 16 + quad * 4;
            const int n = n0 + wn * 32 + ni * 16 + c16;
            const float b0 = bc[n];
            #pragma unroll
            for (int r = 0; r < 4; ++r)
                dout[(size_t)(m + r) * 1024 + n] = acc[mi][ni][r] + b0;
        }
    }
}

// ---------------------------------------------------------------------------
// Fused relative attention, 64-row tiles, 512 threads (8 waves),
// COLUMN-HALVED: two passes over 512-col halves; P-LDS 64x512 = 64 KiB ->
// 2 blocks/CU (4 waves/SIMD) for latency hiding at ~equal total work.
// Grid (bh, i0-tile): block ids of one head congruent mod 8 -> same XCD.
//
// Rel-shift: raw[j][l] -> col cc=(l+j+1)&1023, row j (wrapped) else j-1.
// Per half, the needed raw-l values form a 576-wide window mod 1024 ->
// 37 l-tiles statically split across 8 waves (5/5/5/5/5/4/4/4); stores
// masked to the half. PV accumulates in registers across passes; row
// sums accumulate too. Qu pre-scaled by log2e/32; exp2(bd'+ac') direct.
// ---------------------------------------------------------------------------
__device__ __forceinline__ int lidx9(int row, int c) {
    return (row << 9) + ((((c >> 3) ^ row) << 3) | (c & 7));
}

__global__ __launch_bounds__(512, 2) void attn_kernel(
    const __hip_bfloat16* __restrict__ Qu,   // [4096][1024] (q+bq+u)*C1
    const __hip_bfloat16* __restrict__ Kb,   // [4096][1024]
    const __hip_bfloat16* __restrict__ Posb, // [4096][1024] bf16 pos
    const __hip_bfloat16* __restrict__ Vt,   // [bh*64+d][s]
    const float* __restrict__ uvec, const float* __restrict__ vvec,
    __hip_bfloat16* __restrict__ O)          // [4096][1024]
{
    __shared__ __attribute__((aligned(16))) __hip_bfloat16 Ls[64 * 512]; // 64 KiB
    __shared__ float Wsum[64 * 8];             // per-(row, wave) partial sums
    __shared__ float rs[64];                   // per-row 1/sum

    const int tid  = threadIdx.x;
    const int lane = tid & 63, w = tid >> 6;   // w in [0,8)
    const int quad = lane >> 4, c16 = lane & 15;
    const int i0 = blockIdx.y * 64;            // row tile
    const int bh = blockIdx.x;                 // head (XCD-local: id % 8 = bh % 8)
    const int b = bh >> 4, h = bh & 15;
    const size_t headoff = (size_t)h * 64;
    const size_t tokbase = (size_t)b * 1024;
    const int j2 = i0 + 64;
    const bool havej2 = (j2 < 1024);

    // Per-group Qu fragment pointers (group g = rows i0+g*16 .. +15).
    const __hip_bfloat16* qup0 =
        Qu + (tokbase + i0 + c16) * 1024 + headoff + quad * 8;

    // Phase-2 l-tile split: 37 tiles over 8 waves.
    const int ntile = (w < 5) ? 5 : 4;
    const int tbase = (w < 5) ? w * 5 : 25 + (w - 5) * 4;

    // PV accumulator and row-sum accumulate ACROSS the two passes.
    f32x4 obacc[4] = {};
    float rsum[4] = {0.f, 0.f, 0.f, 0.f};
    const int d0 = (w & 3) * 16;
    const int kh = w >> 2;
    const __hip_bfloat16* vp =
        Vt + ((size_t)bh * 64 + d0 + c16) * 1024 + quad * 8;

    for (int ph = 0; ph < 2; ++ph) {
        const int h0 = ph << 9;

        // Zero col for rows whose (i+1) falls in this half.
        if (tid < 64) {
            const int c = i0 + tid + 1;
            if (c < 1024 && ((c ^ h0) & 512) == 0)
                Ls[lidx9(tid, c & 511)] = __float2bfloat16(0.f);
        }

        // Load au frags; derive av = au + (v-u)*C1 in-register (per pass
        // to keep liveness short; loads are L2/L1-hot).
        float dvuA[8], dvuB[8];
        #pragma unroll
        for (int j = 0; j < 8; ++j) {
            const int d = quad * 8 + j;
            dvuA[j] = (vvec[d]      - uvec[d])      * C1F;
            dvuB[j] = (vvec[d + 32] - uvec[d + 32]) * C1F;
        }
        bf16x8 au[4][2], av[4][2];
        #pragma unroll
        for (int g = 0; g < 4; ++g) {
            au[g][0] = ldg8(qup0 + (size_t)g * 16 * 1024);
            au[g][1] = ldg8(qup0 + (size_t)g * 16 * 1024 + 32);
            #pragma unroll
            for (int j = 0; j < 8; ++j) {
                av[g][0][j] = f2b(b2f(au[g][0][j]) + dvuA[j]);
                av[g][1][j] = f2b(b2f(au[g][1][j]) + dvuB[j]);
            }
        }
        bf16x8 a4[2];
        if (havej2) {
            a4[0] = ldg8(qup0 + (size_t)64 * 1024);
            a4[1] = ldg8(qup0 + (size_t)64 * 1024 + 32);
            #pragma unroll
            for (int j = 0; j < 8; ++j) {
                a4[0][j] = f2b(b2f(a4[0][j]) + dvuA[j]);
                a4[1][j] = f2b(b2f(a4[1][j]) + dvuB[j]);
            }
        }

        // Phase 2: windowed BD scatter for this half.
        // Window start: l = (h0 - i0 - 65) mod 1024, aligned down to tile.
        const int Tstart = ((h0 - i0 - 65) & 1023) >> 4;
        for (int s = 0; s < ntile; ++s) {
            const int tl = (Tstart + tbase + s) & 63;
            const int l0 = tl << 4;
            const __hip_bfloat16* rp =
                Posb + (tokbase + l0 + c16) * 1024 + headoff + quad * 8;
            const bf16x8 r0 = ldg8(rp);
            const bf16x8 r1 = ldg8(rp + 32);
            const int lq = l0 + quad * 4;
            #pragma unroll
            for (int g = 0; g < 4; ++g) {
                f32x4 c = (f32x4){0.f, 0.f, 0.f, 0.f};
                c = MFMA16(r0, av[g][0], c);
                c = MFMA16(r1, av[g][1], c);
                const int jl = g * 16 + c16;
                const int base2 = lq + i0 + jl + 1;   // l + j + 1 at r=0
                const int rwm1 = jl - 1;
                #pragma unroll
                for (int r = 0; r < 4; ++r) {
                    const int t1 = base2 + r;         // <= 2047
                    const int cc = t1 & 1023;
                    const int rw = rwm1 + (t1 >> 10); // +1 iff wrapped
                    if (rw >= 0 && ((cc ^ h0) & 512) == 0)
                        Ls[lidx9(rw, cc & 511)] = __float2bfloat16(c[r]);
                }
            }
            if (havej2) {
                f32x4 c = (f32x4){0.f, 0.f, 0.f, 0.f};
                c = MFMA16(r0, a4[0], c);
                c = MFMA16(r1, a4[1], c);
                if (c16 == 0) {
                    #pragma unroll
                    for (int r = 0; r < 4; ++r) {
                        const int t1 = lq + r + j2 + 1;  // non-wrapped only
                        if (t1 < 1024 && ((t1 ^ h0) & 512) == 0)
                            Ls[lidx9(63, t1 & 511)] = __float2bfloat16(c[r]);
                    }
                }
            }
        }
        __syncthreads();

        // Phase 4: AC' + exp2 for this half's 512 cols (wave strip = 64).
        for (int t = 0; t < 4; ++t) {
            const int c0 = h0 + w * 64 + t * 16;
            const __hip_bfloat16* kp =
                Kb + (tokbase + c0 + c16) * 1024 + headoff + quad * 8;
            const bf16x8 k0 = ldg8(kp);
            const bf16x8 k1 = ldg8(kp + 32);
            const int lc0 = w * 64 + t * 16 + quad * 4;   // local col
            #pragma unroll
            for (int g = 0; g < 4; ++g) {
                f32x4 c = (f32x4){0.f, 0.f, 0.f, 0.f};
                c = MFMA16(k0, au[g][0], c);
                c = MFMA16(k1, au[g][1], c);
                const int jl = g * 16 + c16;
                const int idx = lidx9(jl, lc0);
                const u16x4 bd = *(const u16x4*)&Ls[idx];
                u16x4 pk;
                float s4 = 0.f;
                #pragma unroll
                for (int r = 0; r < 4; ++r) {
                    const float p =
                        __builtin_amdgcn_exp2f(bu2f(bd[r]) + c[r]);
                    s4 += p;
                    pk[r] = f2bu(p);
                }
                *(u16x4*)&Ls[idx] = pk;
                rsum[g] += s4;
            }
        }
        if (ph == 1) {
            // row jl lives in lanes {c16, c16+16, c16+32, c16+48}
            #pragma unroll
            for (int g = 0; g < 4; ++g) {
                float s = rsum[g];
                s += __shfl_xor(s, 16);
                s += __shfl_xor(s, 32);
                if (lane < 16) Wsum[(g * 16 + lane) * 8 + w] = s;
            }
        }
        __syncthreads();

        // rs = 1/rowsum, once Wsum complete (wave-0 lanes; ordered by the
        // phase-4 barrier above and consumed after the post-PV barrier).
        if (ph == 1 && tid < 64) {
            float s = 0.f;
            #pragma unroll
            for (int k = 0; k < 8; ++k) s += Wsum[tid * 8 + k];
            rs[tid] = 1.f / s;
        }

        // Phase 6 partial: PV over this half's 512 cols (kh-half of them
        // per wave), accumulating into obacc across passes.
        for (int kk = kh * 256; kk < kh * 256 + 256; kk += 32) {
            const bf16x8 vld = ldg8(vp + h0 + kk);
            #pragma unroll
            for (int g = 0; g < 4; ++g) {
                const bf16x8 p =
                    *(const bf16x8*)&Ls[lidx9(g * 16 + c16, kk + quad * 8)];
                obacc[g] = MFMA16(p, vld, obacc[g]);
            }
        }
        __syncthreads();   // PV reads done; Ls reusable next pass / epilogue
    }

    // Epilogue: kh=1 waves dump partial O to LDS; kh=0 combines, scales,
    // writes.
    float* Lf = (float*)Ls;
    const int sbase = (w & 3) * 1024;
    if (kh == 1) {
        #pragma unroll
        for (int g = 0; g < 4; ++g)
            #pragma unroll
            for (int r = 0; r < 4; ++r)
                Lf[sbase + g * 256 + (quad * 4 + r) * 16 + c16] = obacc[g][r];
    }
    __syncthreads();
    if (kh == 0) {
        #pragma unroll
        for (int g = 0; g < 4; ++g)
            #pragma unroll
            for (int r = 0; r < 4; ++r) {
                const int il = g * 16 + quad * 4 + r;
                const float val =
                    (obacc[g][r] + Lf[sbase + g * 256 + (quad * 4 + r) * 16 + c16])
                    * rs[il];
                const int i = i0 + il;
                const int d = d0 + c16;
                O[(tokbase + i) * 1024 + headoff + d] = __float2bfloat16(val);
            }
    }
}

// ---------------------------------------------------------------------------
extern "C" void kernel_launch(void* const* d_in, const int* in_sizes, int n_in,
                              void* d_out, int out_size, void* d_ws, size_t ws_size,
                              hipStream_t stream)
{
    const float* x   = (const float*)d_in[0];
    const float* u   = (const float*)d_in[1];
    const float* v   = (const float*)d_in[2];
    const float* pos = (const float*)d_in[3];
    const float* Wq  = (const float*)d_in[4];
    const float* bq  = (const float*)d_in[5];
    const float* Wk  = (const float*)d_in[6];
    const float* bk  = (const float*)d_in[7];
    const float* Wv  = (const float*)d_in[8];
    const float* bv  = (const float*)d_in[9];
    const float* Wc  = (const float*)d_in[10];
    const float* bc  = (const float*)d_in[11];

    const size_t MB = (size_t)1 << 20;
    char* ws = (char*)d_ws;
    __hip_bfloat16* Qu    = (__hip_bfloat16*)(ws + 0 * MB);
    __hip_bfloat16* Kb    = (__hip_bfloat16*)(ws + 8 * MB);
    __hip_bfloat16* Vt    = (__hip_bfloat16*)(ws + 16 * MB);
    __hip_bfloat16* xb    = (__hip_bfloat16*)(ws + 24 * MB);  // aliased w/ O
    __hip_bfloat16* O     = (__hip_bfloat16*)(ws + 24 * MB);  // x dead after QKV
    __hip_bfloat16* Posb  = (__hip_bfloat16*)(ws + 32 * MB);
    __hip_bfloat16* Wqkvb = (__hip_bfloat16*)(ws + 40 * MB);
    __hip_bfloat16* Wcb   = (__hip_bfloat16*)(ws + 46 * MB);

    cvt_kernel<<<6144, 256, 0, stream>>>(x, pos, Wq, Wk, Wv, Wc,
                                         xb, Posb, Wqkvb, Wcb);

    gemm_qkv<<<dim3(24, 32), dim3(256), 0, stream>>>(
        xb, Wqkvb, bq, bk, bv, u, Qu, Kb, Vt);

    attn_kernel<<<dim3(64, 16), dim3(512), 0, stream>>>(
        Qu, Kb, Posb, Vt, u, v, O);

    gemm_fin64<<<dim3(16, 64), dim3(256), 0, stream>>>(
        O, Wcb, (float*)d_out, bc);
}

// Round 8
// 249.575 us; speedup vs baseline: 1.5977x; 1.1269x over previous
//
#include <hip/hip_runtime.h>
#include <hip/hip_bf16.h>

// RelAttention (Transformer-XL style) on MI355X.
// fp32 in/out; internal bf16 MFMA w/ fp32 accum.
// B=4, S=1024, D=1024, H=16, DH=64, BH=64. SCALE = 1/32.
//
// Pipeline: cvt -> fused QKV GEMM (m97-style; Q PRE-SCALED by log2e/32;
// V store routed through LDS for coalesced writes) -> fused rel-attention
// (r3 structure: 64-row tiles, 8 waves, swapped-operand MFMA, packed
// u16x4 LDS, + K/Pos tile prefetch) -> final GEMM (64x64, 4 blocks/CU).
//
// Learned constraints (r1/r4/r5/r6): occupancy is NOT the attn lever —
// barrier-locked phases stall all resident waves together (r6: 16 waves
// = slower; r1: 2 blocks @ halved tile = slower). __launch_bounds__ VGPR
// cap is 256/min_waves (r4: (512,4)->64 cap -> 900 MB spill).
// r7 bug fixed here: V^T column is the IN-BATCH token (m0 & 1023), not
// the global row m0 — using m0 shifted writes by (m0>>10) rows for
// batches 1-3 and overflowed the Vt region.

typedef __bf16 bf16x8 __attribute__((ext_vector_type(8)));
typedef float  f32x4  __attribute__((ext_vector_type(4)));
typedef unsigned short u16x4 __attribute__((ext_vector_type(4)));

struct alignas(16) U128 { unsigned long long lo, hi; };

__device__ __forceinline__ bf16x8 ldg8(const __hip_bfloat16* p) {
    U128 u = *reinterpret_cast<const U128*>(p);
    return __builtin_bit_cast(bf16x8, u);
}

__device__ __forceinline__ __bf16 f2b(float f) {
    __hip_bfloat16 h = __float2bfloat16(f);
    return __builtin_bit_cast(__bf16, h);
}
__device__ __forceinline__ unsigned short f2bu(float f) {
    __hip_bfloat16 h = __float2bfloat16(f);
    return __builtin_bit_cast(unsigned short, h);
}
__device__ __forceinline__ float b2f(__bf16 b) {
    __hip_bfloat16 h = __builtin_bit_cast(__hip_bfloat16, b);
    return __bfloat162float(h);
}
__device__ __forceinline__ float bu2f(unsigned short u) {
    __hip_bfloat16 h = __builtin_bit_cast(__hip_bfloat16, u);
    return __bfloat162float(h);
}

__device__ __forceinline__ bf16x8 ldg8cvt(const float* p) {
    f32x4 a = *reinterpret_cast<const f32x4*>(p);
    f32x4 b = *reinterpret_cast<const f32x4*>(p + 4);
    bf16x8 r;
    r[0] = f2b(a[0]); r[1] = f2b(a[1]); r[2] = f2b(a[2]); r[3] = f2b(a[3]);
    r[4] = f2b(b[0]); r[5] = f2b(b[1]); r[6] = f2b(b[2]); r[7] = f2b(b[3]);
    return r;
}

#define MFMA16(a, b, c) __builtin_amdgcn_mfma_f32_16x16x32_bf16((a), (b), (c), 0, 0, 0)

// C1 = log2(e) * SCALE = log2(e)/32. Q is pre-scaled by this so the
// softmax exponent is exp2(bd' + ac') with NO fma and NO shift constant.
#define C1F 0.0450843334f

__device__ __forceinline__ void gll16(const __hip_bfloat16* g, void* lds_wave_base) {
    __builtin_amdgcn_global_load_lds(
        (const __attribute__((address_space(1))) void*)g,
        (__attribute__((address_space(3))) void*)lds_wave_base,
        16, 0, 0);
}

// ---------------------------------------------------------------------------
// fp32 -> bf16: x(4M), pos(4M), Wq/Wk/Wv(3M stacked), Wc(1M) = 12M elems.
// ---------------------------------------------------------------------------
__global__ __launch_bounds__(256) void cvt_kernel(
    const float* __restrict__ x,  const float* __restrict__ pos,
    const float* __restrict__ wq, const float* __restrict__ wk,
    const float* __restrict__ wv, const float* __restrict__ wc,
    __hip_bfloat16* __restrict__ xb, __hip_bfloat16* __restrict__ posb,
    __hip_bfloat16* __restrict__ wqkvb, __hip_bfloat16* __restrict__ wcb)
{
    const size_t base = ((size_t)blockIdx.x * 256 + threadIdx.x) * 8;
    const size_t M1 = (size_t)1 << 20;
    const float* src; __hip_bfloat16* dst; size_t o;
    if (base < 4*M1)        { src = x;   dst = xb;           o = base; }
    else if (base < 8*M1)   { src = pos; dst = posb;         o = base - 4*M1; }
    else if (base < 9*M1)   { src = wq;  dst = wqkvb;        o = base - 8*M1; }
    else if (base < 10*M1)  { src = wk;  dst = wqkvb + M1;   o = base - 9*M1; }
    else if (base < 11*M1)  { src = wv;  dst = wqkvb + 2*M1; o = base - 10*M1; }
    else                    { src = wc;  dst = wcb;          o = base - 11*M1; }
    *(bf16x8*)(dst + o) = ldg8cvt(src + o);
}

// ---------------------------------------------------------------------------
// QKV GEMM (m97-style): C[m][n] = sum_k A[m][k]*Bm[n][k], Bm=[3072][1024].
// n<1024 -> Qu = (C+bq+u)*C1 (PRE-SCALED); <2048 -> Kb = C+bk;
// else Vt head-transposed = C+bv, routed through LDS so the global write
// is coalesced (direct store was 64 lanes x 8B at 2KB stride).
// ---------------------------------------------------------------------------
__global__ __launch_bounds__(256) void gemm_qkv(
    const __hip_bfloat16* __restrict__ A,
    const __hip_bfloat16* __restrict__ Bm,
    const float* __restrict__ bq, const float* __restrict__ bk,
    const float* __restrict__ bv, const float* __restrict__ u,
    __hip_bfloat16* __restrict__ Qu,
    __hip_bfloat16* __restrict__ Kb, __hip_bfloat16* __restrict__ Vt)
{
    // Union: staging (As 4096 + Bs 4096 elems) during K-loop; V-transpose
    // tile [128][132] (pad +4 breaks bank alignment) in the epilogue.
    __shared__ __attribute__((aligned(16))) __hip_bfloat16 Smem[128 * 132];
    __hip_bfloat16* As = Smem;
    __hip_bfloat16* Bs = Smem + 4096;

    const int tid  = threadIdx.x;
    const int lane = tid & 63, w = tid >> 6;
    const int quad = lane >> 4, c16 = lane & 15;
    const int wm = w >> 1, wn = w & 1;
    const int m0 = blockIdx.y * 128;
    const int n0 = blockIdx.x * 128;

    const int srow = w * 16 + (lane >> 2);
    const int scol = (lane & 3) * 8;
    const __hip_bfloat16* gA0 = A  + (size_t)(m0 + srow) * 1024 + scol;
    const __hip_bfloat16* gA1 = gA0 + (size_t)64 * 1024;
    const __hip_bfloat16* gB0 = Bm + (size_t)(n0 + srow) * 1024 + scol;
    const __hip_bfloat16* gB1 = gB0 + (size_t)64 * 1024;
    char* ldsA0 = (char*)As + (w << 10);
    char* ldsA1 = ldsA0 + 4096;
    char* ldsB0 = (char*)Bs + (w << 10);
    char* ldsB1 = ldsB0 + 4096;

    f32x4 acc[4][4] = {};

    for (int k0 = 0; k0 < 1024; k0 += 32) {
        gll16(gA0 + k0, ldsA0);
        gll16(gA1 + k0, ldsA1);
        gll16(gB0 + k0, ldsB0);
        gll16(gB1 + k0, ldsB1);
        __syncthreads();

        bf16x8 af[4], bfr[4];
        #pragma unroll
        for (int i = 0; i < 4; ++i) {
            af[i]  = *(const bf16x8*)&As[(wm * 64 + i * 16 + c16) * 32 + quad * 8];
            bfr[i] = *(const bf16x8*)&Bs[(wn * 64 + i * 16 + c16) * 32 + quad * 8];
        }
        #pragma unroll
        for (int mi = 0; mi < 4; ++mi)
            #pragma unroll
            for (int ni = 0; ni < 4; ++ni)
                acc[mi][ni] = MFMA16(af[mi], bfr[ni], acc[mi][ni]);
        __syncthreads();
    }

    if (n0 < 2048) {
        #pragma unroll
        for (int mi = 0; mi < 4; ++mi) {
            #pragma unroll
            for (int ni = 0; ni < 4; ++ni) {
                const int m = m0 + wm * 64 + mi * 16 + quad * 4;  // +r
                const int n = n0 + wn * 64 + ni * 16 + c16;
                if (n < 1024) {
                    const float b0 = bq[n] + u[n & 63];
                    #pragma unroll
                    for (int r = 0; r < 4; ++r)
                        Qu[(size_t)(m + r) * 1024 + n] =
                            __float2bfloat16((acc[mi][ni][r] + b0) * C1F);
                } else {
                    const int nn = n - 1024;
                    const float b0 = bk[nn];
                    #pragma unroll
                    for (int r = 0; r < 4; ++r)
                        Kb[(size_t)(m + r) * 1024 + nn] =
                            __float2bfloat16(acc[mi][ni][r] + b0);
                }
            }
        }
    } else {
        // V epilogue: stage transposed into LDS, write coalesced.
        // Vs[nl][ml], nl = local n (0..127), ml = local m (0..127),
        // row stride 132 elems. acc packs ml..ml+3 per u16x4.
        const int mlb = wm * 64 + quad * 4;
        #pragma unroll
        for (int ni = 0; ni < 4; ++ni) {
            const int nl = wn * 64 + ni * 16 + c16;
            const float b0 = bv[(n0 - 2048 + nl) & 1023];
            #pragma unroll
            for (int mi = 0; mi < 4; ++mi) {
                u16x4 pk;
                #pragma unroll
                for (int r = 0; r < 4; ++r)
                    pk[r] = f2bu(acc[mi][ni][r] + b0);
                *(u16x4*)&Smem[nl * 132 + mlb + mi * 16] = pk;
            }
        }
        __syncthreads();
        // Wave w writes rows nl = w*32..+31; 64 lanes x 4B = 256B/row.
        // Column base is the IN-BATCH token (m0 & 1023) — r7 bug was m0.
        const int bb = m0 >> 10;
        const int hh0 = (n0 - 2048) >> 6;
        const int s0 = m0 & 1023;
        for (int i = 0; i < 32; ++i) {
            const int nl = w * 32 + i;
            const int R = (bb * 16 + hh0 + (nl >> 6)) * 64 + (nl & 63);
            const unsigned int val =
                *(const unsigned int*)&Smem[nl * 132 + lane * 2];
            *(unsigned int*)&Vt[(size_t)R * 1024 + s0 + lane * 2] = val;
        }
    }
}

// ---------------------------------------------------------------------------
// Final GEMM, 64x64 tiles (grid 16x64 = 1024 blocks -> 4 blocks/CU).
// ---------------------------------------------------------------------------
__global__ __launch_bounds__(256) void gemm_fin64(
    const __hip_bfloat16* __restrict__ A,
    const __hip_bfloat16* __restrict__ Bm,
    float* __restrict__ dout, const float* __restrict__ bc)
{
    __shared__ __hip_bfloat16 As[64 * 32];
    __shared__ __hip_bfloat16 Bs[64 * 32];

    const int tid  = threadIdx.x;
    const int lane = tid & 63, w = tid >> 6;
    const int quad = lane >> 4, c16 = lane & 15;
    const int wm = w >> 1, wn = w & 1;
    const int m0 = blockIdx.y * 64;
    const int n0 = blockIdx.x * 64;

    const int srow = w * 16 + (lane >> 2);
    const int scol = (lane & 3) * 8;
    const __hip_bfloat16* gA = A  + (size_t)(m0 + srow) * 1024 + scol;
    const __hip_bfloat16* gB = Bm + (size_t)(n0 + srow) * 1024 + scol;
    char* ldsA = (char*)As + (w << 10);
    char* ldsB = (char*)Bs + (w << 10);

    f32x4 acc[2][2] = {};

    for (int k0 = 0; k0 < 1024; k0 += 32) {
        gll16(gA + k0, ldsA);
        gll16(gB + k0, ldsB);
        __syncthreads();

        bf16x8 af[2], bfr[2];
        #pragma unroll
        for (int i = 0; i < 2; ++i) {
            af[i]  = *(const bf16x8*)&As[(wm * 32 + i * 16 + c16) * 32 + quad * 8];
            bfr[i] = *(const bf16x8*)&Bs[(wn * 32 + i * 16 + c16) * 32 + quad * 8];
        }
        #pragma unroll
        for (int mi = 0; mi < 2; ++mi)
            #pragma unroll
            for (int ni = 0; ni < 2; ++ni)
                acc[mi][ni] = MFMA16(af[mi], bfr[ni], acc[mi][ni]);
        __syncthreads();
    }

    #pragma unroll
    for (int mi = 0; mi < 2; ++mi) {
        #pragma unroll
        for (int ni = 0; ni < 2; ++ni) {
            const int m = m0 + wm * 32 + mi * 16 + quad * 4;
            const int n = n0 + wn * 32 + ni * 16 + c16;
            const float b0 = bc[n];
            #pragma unroll
            for (int r = 0; r < 4; ++r)
                dout[(size_t)(m + r) * 1024 + n] = acc[mi][ni][r] + b0;
        }
    }
}

// ---------------------------------------------------------------------------
// Fused relative attention — r3 structure (proven 105.7 us) + K/Pos tile
// prefetch. 64-row tiles, 512 threads (8 waves), LDS 128 KiB P ->
// 1 block/CU. Grid (bh, i0-tile): block ids of one head congruent mod 8
// -> same XCD -> K/Pos/V stay hot in that XCD's L2.
//
// Qu arrives PRE-SCALED by C1=log2e/32; softmax is exp2(bd'+ac').
// Qu fragments loaded ONCE; Qv = au + (v-u)*C1 derived in-register.
// Rel-shift: raw[j][l] -> col cc=(l+j+1)&1023, row j (wrapped) else j-1;
// (j, j+1) is the injected zero. Raw row j2=i0+64 via extra MFMA
// (q_{j2} in col 0 of B; c16==0 lanes scatter).
// ---------------------------------------------------------------------------
__device__ __forceinline__ int lidx16(int row, int c) {
    return (row << 10) + ((((c >> 3) ^ row) << 3) | (c & 7));
}

__global__ __launch_bounds__(512, 2) void attn_kernel(
    const __hip_bfloat16* __restrict__ Qu,   // [4096][1024] (q+bq+u)*C1
    const __hip_bfloat16* __restrict__ Kb,   // [4096][1024]
    const __hip_bfloat16* __restrict__ Posb, // [4096][1024] bf16 pos
    const __hip_bfloat16* __restrict__ Vt,   // [bh*64+d][s]
    const float* __restrict__ uvec, const float* __restrict__ vvec,
    __hip_bfloat16* __restrict__ O)          // [4096][1024]
{
    __shared__ __attribute__((aligned(16))) __hip_bfloat16 Ls[64 * 1024]; // 128 KiB
    __shared__ float Wsum[64 * 8];             // per-(row, wave) partial sums
    __shared__ float rs[64];                   // per-row 1/sum

    const int tid  = threadIdx.x;
    const int lane = tid & 63, w = tid >> 6;   // w in [0,8)
    const int quad = lane >> 4, c16 = lane & 15;
    const int i0 = blockIdx.y * 64;            // row tile
    const int bh = blockIdx.x;                 // head (XCD-local: id % 8 = bh % 8)
    const int b = bh >> 4, h = bh & 15;
    const size_t headoff = (size_t)h * 64;
    const size_t tokbase = (size_t)b * 1024;
    const int j2 = i0 + 64;
    const bool havej2 = (j2 < 1024);

    // Phase 1: the rel-shift leaves exactly one zero per row, at c = i+1.
    if (tid < 64) {
        const int i = i0 + tid;
        if (i + 1 < 1024) Ls[lidx16(tid, i + 1)] = __float2bfloat16(0.f);
    }

    // Per-group Qu fragment pointers (group g = rows i0+g*16 .. +15).
    const __hip_bfloat16* qup0 =
        Qu + (tokbase + i0 + c16) * 1024 + headoff + quad * 8;

    // Load Qu frags ONCE; derive Qv frags = au + (v-u)*C1 in-register.
    float dvuA[8], dvuB[8];
    #pragma unroll
    for (int j = 0; j < 8; ++j) {
        const int d = quad * 8 + j;
        dvuA[j] = (vvec[d]      - uvec[d])      * C1F;
        dvuB[j] = (vvec[d + 32] - uvec[d + 32]) * C1F;
    }
    bf16x8 au[4][2], av[4][2];
    #pragma unroll
    for (int g = 0; g < 4; ++g) {
        au[g][0] = ldg8(qup0 + (size_t)g * 16 * 1024);
        au[g][1] = ldg8(qup0 + (size_t)g * 16 * 1024 + 32);
        #pragma unroll
        for (int j = 0; j < 8; ++j) {
            av[g][0][j] = f2b(b2f(au[g][0][j]) + dvuA[j]);
            av[g][1][j] = f2b(b2f(au[g][1][j]) + dvuB[j]);
        }
    }

    // Phase 2: BD'_raw = r . (qv)^T  (swapped: lane = row j fixed, 4
    // consecutive l). Scatter: col cc = (l+j+1)&1023, row j (wrapped) or
    // j-1 (not). Extra group for raw row j2. Next Pos tile prefetched.
    {
        bf16x8 a4[2];
        if (havej2) {
            a4[0] = ldg8(qup0 + (size_t)64 * 1024);
            a4[1] = ldg8(qup0 + (size_t)64 * 1024 + 32);
            #pragma unroll
            for (int j = 0; j < 8; ++j) {
                a4[0][j] = f2b(b2f(a4[0][j]) + dvuA[j]);
                a4[1][j] = f2b(b2f(a4[1][j]) + dvuB[j]);
            }
        }
        const __hip_bfloat16* rpb =
            Posb + (tokbase + w * 128 + c16) * 1024 + headoff + quad * 8;
        bf16x8 r0 = ldg8(rpb);
        bf16x8 r1 = ldg8(rpb + 32);
        for (int t = 0; t < 8; ++t) {
            const int tn = (t + 1) & 7;              // prefetch next tile
            const bf16x8 p0 = ldg8(rpb + (size_t)tn * 16 * 1024);
            const bf16x8 p1 = ldg8(rpb + (size_t)tn * 16 * 1024 + 32);
            const int lq = w * 128 + t * 16 + quad * 4;
            #pragma unroll
            for (int g = 0; g < 4; ++g) {
                f32x4 c = (f32x4){0.f, 0.f, 0.f, 0.f};
                c = MFMA16(r0, av[g][0], c);
                c = MFMA16(r1, av[g][1], c);
                const int jl = g * 16 + c16;
                const int base2 = lq + i0 + jl + 1;   // l + j + 1 at r=0
                const int rwm1 = jl - 1;
                #pragma unroll
                for (int r = 0; r < 4; ++r) {
                    const int t1 = base2 + r;         // <= 2047
                    const int cc = t1 & 1023;
                    const int rw = rwm1 + (t1 >> 10); // +1 iff wrapped
                    if (rw >= 0)
                        Ls[lidx16(rw, cc)] = __float2bfloat16(c[r]);
                }
            }
            if (havej2) {
                f32x4 c = (f32x4){0.f, 0.f, 0.f, 0.f};
                c = MFMA16(r0, a4[0], c);
                c = MFMA16(r1, a4[1], c);
                if (c16 == 0) {
                    #pragma unroll
                    for (int r = 0; r < 4; ++r) {
                        const int cc = lq + r + i0 + 65;  // l + j2 + 1
                        if (cc < 1024)
                            Ls[lidx16(63, cc)] = __float2bfloat16(c[r]);
                    }
                }
            }
            r0 = p0; r1 = p1;
        }
    }
    __syncthreads();

    // Phase 4: AC' = k . (qu)^T; packed b64 BD read -> fused exp2 ->
    // packed b64 P write in place. Next K tile prefetched.
    {
        const __hip_bfloat16* kpb =
            Kb + (tokbase + w * 128 + c16) * 1024 + headoff + quad * 8;
        bf16x8 k0 = ldg8(kpb);
        bf16x8 k1 = ldg8(kpb + 32);
        float rsum[4] = {0.f, 0.f, 0.f, 0.f};
        for (int t = 0; t < 8; ++t) {
            const int tn = (t + 1) & 7;              // prefetch next tile
            const bf16x8 p0 = ldg8(kpb + (size_t)tn * 16 * 1024);
            const bf16x8 p1 = ldg8(kpb + (size_t)tn * 16 * 1024 + 32);
            const int cc0 = w * 128 + t * 16 + quad * 4;
            #pragma unroll
            for (int g = 0; g < 4; ++g) {
                f32x4 c = (f32x4){0.f, 0.f, 0.f, 0.f};
                c = MFMA16(k0, au[g][0], c);
                c = MFMA16(k1, au[g][1], c);
                const int jl = g * 16 + c16;
                const int idx = lidx16(jl, cc0);
                const u16x4 bd = *(const u16x4*)&Ls[idx];
                u16x4 pk;
                float s4 = 0.f;
                #pragma unroll
                for (int r = 0; r < 4; ++r) {
                    const float p =
                        __builtin_amdgcn_exp2f(bu2f(bd[r]) + c[r]);
                    s4 += p;
                    pk[r] = f2bu(p);
                }
                *(u16x4*)&Ls[idx] = pk;
                rsum[g] += s4;          // shuffles hoisted out of the loop
            }
            k0 = p0; k1 = p1;
        }
        // row jl lives in lanes {c16, c16+16, c16+32, c16+48}
        #pragma unroll
        for (int g = 0; g < 4; ++g) {
            float s = rsum[g];
            s += __shfl_xor(s, 16);
            s += __shfl_xor(s, 32);
            if (lane < 16) Wsum[(g * 16 + lane) * 8 + w] = s;
        }
    }
    __syncthreads();

    if (tid < 64) {
        float s = 0.f;
        #pragma unroll
        for (int k = 0; k < 8; ++k) s += Wsum[tid * 8 + k];
        rs[tid] = 1.f / s;
    }
    __syncthreads();

    // Phase 6: O = (P @ V) * rinv for all 4 row groups.
    // Wave w: d-tile d0=(w&3)*16, k-half kh=w>>2; V load shared by groups.
    {
        const int d0 = (w & 3) * 16;
        const int kh = w >> 2;
        const __hip_bfloat16* vp =
            Vt + ((size_t)bh * 64 + d0 + c16) * 1024 + quad * 8;
        f32x4 acc[4] = {};
        for (int kk = kh * 512; kk < kh * 512 + 512; kk += 32) {
            const bf16x8 vld = ldg8(vp + kk);
            #pragma unroll
            for (int g = 0; g < 4; ++g) {
                const bf16x8 p =
                    *(const bf16x8*)&Ls[lidx16(g * 16 + c16, kk + quad * 8)];
                acc[g] = MFMA16(p, vld, acc[g]);
            }
        }
        __syncthreads();   // all P reads done; logits LDS now reusable
        float* Lf = (float*)Ls;
        const int sbase = (w & 3) * 1024;
        if (kh == 1) {
            #pragma unroll
            for (int g = 0; g < 4; ++g)
                #pragma unroll
                for (int r = 0; r < 4; ++r)
                    Lf[sbase + g * 256 + (quad * 4 + r) * 16 + c16] = acc[g][r];
        }
        __syncthreads();
        if (kh == 0) {
            #pragma unroll
            for (int g = 0; g < 4; ++g)
                #pragma unroll
                for (int r = 0; r < 4; ++r) {
                    const int il = g * 16 + quad * 4 + r;
                    const float val =
                        (acc[g][r] + Lf[sbase + g * 256 + (quad * 4 + r) * 16 + c16])
                        * rs[il];
                    const int i = i0 + il;
                    const int d = d0 + c16;
                    O[(tokbase + i) * 1024 + headoff + d] = __float2bfloat16(val);
                }
        }
    }
}

// ---------------------------------------------------------------------------
extern "C" void kernel_launch(void* const* d_in, const int* in_sizes, int n_in,
                              void* d_out, int out_size, void* d_ws, size_t ws_size,
                              hipStream_t stream)
{
    const float* x   = (const float*)d_in[0];
    const float* u   = (const float*)d_in[1];
    const float* v   = (const float*)d_in[2];
    const float* pos = (const float*)d_in[3];
    const float* Wq  = (const float*)d_in[4];
    const float* bq  = (const float*)d_in[5];
    const float* Wk  = (const float*)d_in[6];
    const float* bk  = (const float*)d_in[7];
    const float* Wv  = (const float*)d_in[8];
    const float* bv  = (const float*)d_in[9];
    const float* Wc  = (const float*)d_in[10];
    const float* bc  = (const float*)d_in[11];

    const size_t MB = (size_t)1 << 20;
    char* ws = (char*)d_ws;
    __hip_bfloat16* Qu    = (__hip_bfloat16*)(ws + 0 * MB);
    __hip_bfloat16* Kb    = (__hip_bfloat16*)(ws + 8 * MB);
    __hip_bfloat16* Vt    = (__hip_bfloat16*)(ws + 16 * MB);
    __hip_bfloat16* xb    = (__hip_bfloat16*)(ws + 24 * MB);  // aliased w/ O
    __hip_bfloat16* O     = (__hip_bfloat16*)(ws + 24 * MB);  // x dead after QKV
    __hip_bfloat16* Posb  = (__hip_bfloat16*)(ws + 32 * MB);
    __hip_bfloat16* Wqkvb = (__hip_bfloat16*)(ws + 40 * MB);
    __hip_bfloat16* Wcb   = (__hip_bfloat16*)(ws + 46 * MB);

    cvt_kernel<<<6144, 256, 0, stream>>>(x, pos, Wq, Wk, Wv, Wc,
                                         xb, Posb, Wqkvb, Wcb);

    gemm_qkv<<<dim3(24, 32), dim3(256), 0, stream>>>(
        xb, Wqkvb, bq, bk, bv, u, Qu, Kb, Vt);

    attn_kernel<<<dim3(64, 16), dim3(512), 0, stream>>>(
        Qu, Kb, Posb, Vt, u, v, O);

    gemm_fin64<<<dim3(16, 64), dim3(256), 0, stream>>>(
        O, Wcb, (float*)d_out, bc);
}